// Round 7
// baseline (2165.590 us; speedup 1.0000x reference)
//
#include <hip/hip_runtime.h>
#include <stdint.h>
#include <stddef.h>

#define MSTEPS 128
#define NB 1024
#define ED 512
#define GD 1536
#define VS 32000

// GRU decomposition (r3-proven): 32 row-blocks x 32 rows, 8 col-WGs x 64 cols.
#define RB 32
#define CB 64
#define NRB 32
#define NCB 8
#define GIST 200 // gi LDS row stride (elems)
#define STST 80  // stl LDS row stride (elems)

typedef __attribute__((ext_vector_type(4))) float f32x4;
typedef __attribute__((ext_vector_type(8))) short s16x8;
typedef __attribute__((ext_vector_type(4))) short s16x4;
typedef __attribute__((ext_vector_type(8))) unsigned short u16x8;

__device__ __forceinline__ unsigned short f2bf(float f) {
  unsigned x = __builtin_bit_cast(unsigned, f);
  x = x + 0x7fffu + ((x >> 16) & 1u);
  return (unsigned short)(x >> 16);
}
__device__ __forceinline__ float bf2f(unsigned short u) {
  return __builtin_bit_cast(float, ((unsigned)u) << 16);
}
__device__ __forceinline__ float sigm(float x) { return 1.0f / (1.0f + __expf(-x)); }
__device__ __forceinline__ float tanh_(float x) {
  x = fminf(15.0f, fmaxf(-15.0f, x));
  float e = __expf(-2.0f * x);
  return (1.0f - e) / (1.0f + e);
}

// ---------------- Kernel 1: projected vocab table (r2-proven) ----------------
__global__ __launch_bounds__(256) void table_kernel(
    const float* __restrict__ emb, const float* __restrict__ Wih,
    const float* __restrict__ bih, unsigned short* __restrict__ tab)
{
  __shared__ short Al[128 * 64];
  __shared__ short Bl[128 * 64];
  const int tid = threadIdx.x;
  const int lane = tid & 63;
  const int l15 = lane & 15, l4 = lane >> 4;
  const int wv = tid >> 6;
  const int rh = wv & 1, ch = wv >> 1;
  const int row0 = blockIdx.x * 128;
  const int col0 = blockIdx.y * 128;

  f32x4 acc[4][4];
  #pragma unroll
  for (int m = 0; m < 4; m++)
    #pragma unroll
    for (int n = 0; n < 4; n++) acc[m][n] = (f32x4){0.f, 0.f, 0.f, 0.f};

  for (int ko = 0; ko < ED; ko += 64) {
    #pragma unroll
    for (int i = 0; i < 8; i++) {
      int idx = tid + i * 256;
      int r = idx >> 4, c4 = idx & 15;
      int ba = (r * 128 + c4 * 8) ^ ((r & 7) << 4);
      f32x4 va = *(const f32x4*)(emb + (size_t)(row0 + r) * ED + ko + c4 * 4);
      s16x4 pa;
      pa[0] = (short)f2bf(va[0]); pa[1] = (short)f2bf(va[1]);
      pa[2] = (short)f2bf(va[2]); pa[3] = (short)f2bf(va[3]);
      *(s16x4*)((char*)Al + ba) = pa;
      f32x4 vb = *(const f32x4*)(Wih + (size_t)(col0 + r) * ED + ko + c4 * 4);
      s16x4 pb;
      pb[0] = (short)f2bf(vb[0]); pb[1] = (short)f2bf(vb[1]);
      pb[2] = (short)f2bf(vb[2]); pb[3] = (short)f2bf(vb[3]);
      *(s16x4*)((char*)Bl + ba) = pb;
    }
    __syncthreads();
    #pragma unroll
    for (int kk = 0; kk < 2; kk++) {
      s16x8 af[4], bfv[4];
      #pragma unroll
      for (int m = 0; m < 4; m++) {
        int row = rh * 64 + m * 16 + l15;
        int ad = (row * 128 + kk * 64 + l4 * 16) ^ ((row & 7) << 4);
        af[m] = *(const s16x8*)((char*)Al + ad);
      }
      #pragma unroll
      for (int n = 0; n < 4; n++) {
        int col = ch * 64 + n * 16 + l15;
        int ad = (col * 128 + kk * 64 + l4 * 16) ^ ((col & 7) << 4);
        bfv[n] = *(const s16x8*)((char*)Bl + ad);
      }
      #pragma unroll
      for (int m = 0; m < 4; m++)
        #pragma unroll
        for (int n = 0; n < 4; n++)
          acc[m][n] = __builtin_amdgcn_mfma_f32_16x16x32_bf16(af[m], bfv[n], acc[m][n], 0, 0, 0);
    }
    __syncthreads();
  }

  float bias_n[4];
  #pragma unroll
  for (int n = 0; n < 4; n++) bias_n[n] = bih[col0 + ch * 64 + n * 16 + l15];
  #pragma unroll
  for (int m = 0; m < 4; m++)
    #pragma unroll
    for (int n = 0; n < 4; n++) {
      int colg = col0 + ch * 64 + n * 16 + l15;
      #pragma unroll
      for (int j = 0; j < 4; j++) {
        int rowg = row0 + rh * 64 + m * 16 + l4 * 4 + j;
        tab[(size_t)rowg * GD + colg] = f2bf(acc[m][n][j] + bias_n[n]);
      }
    }
}

// ---------------- Kernel 2: persistent GRU scan (r3 + flag barrier + s0 skip) ----------------
__global__ __launch_bounds__(256, 1) void gru_kernel(
    const int* __restrict__ utt, const float* __restrict__ Whh,
    const float* __restrict__ bhh, const unsigned short* __restrict__ tab,
    unsigned short* st0, unsigned short* st1,
    unsigned* cnt, const int* __restrict__ termp,
    float* __restrict__ out)
{
  __shared__ __align__(16) char sls[RB * 1024];            // state tile 32KB
  __shared__ __align__(16) unsigned short gil[RB * GIST];  // 12.5KB
  __shared__ __align__(16) unsigned short stl[RB * STST];  // 5KB
  __shared__ int abl;

  const int tid = threadIdx.x;
  const int lane = tid & 63;
  const int l15 = lane & 15, l4 = lane >> 4;
  const int wv = tid >> 6;
  const int bid = blockIdx.x;
  const int rblk = bid & (NRB - 1), cblk = bid >> 5;
  const int r0 = rblk * RB, c0 = cblk * CB;
  const int wc = wv * 16 + l15;            // col within WG tile, 0..63
  const int termid = termp[0];
  const int grow = tid >> 3, gq = tid & 7; // gather: row 0..31, eighth

  unsigned* fl = cnt + rblk * 16;          // 8 flags, one 64B line per group
  int* abort_g = (int*)(cnt + 1024);

  // ---- W_hh fragments -> VGPRs (held for all 128 steps) ----
  s16x8 bfr[3][16];
  #pragma unroll
  for (int g = 0; g < 3; g++)
    #pragma unroll
    for (int kk = 0; kk < 16; kk++) {
      const float* src = Whh + (size_t)(g * ED + c0 + wc) * ED + kk * 32 + l4 * 8;
      f32x4 v0 = *(const f32x4*)(src);
      f32x4 v1 = *(const f32x4*)(src + 4);
      s16x8 p;
      p[0] = (short)f2bf(v0[0]); p[1] = (short)f2bf(v0[1]);
      p[2] = (short)f2bf(v0[2]); p[3] = (short)f2bf(v0[3]);
      p[4] = (short)f2bf(v1[0]); p[5] = (short)f2bf(v1[1]);
      p[6] = (short)f2bf(v1[2]); p[7] = (short)f2bf(v1[3]);
      bfr[g][kk] = p;
    }

  float bh[3];
  #pragma unroll
  for (int g = 0; g < 3; g++) bh[g] = bhh[g * ED + c0 + wc];

  float ms[2][4] = {{0.f, 0.f, 0.f, 0.f}, {0.f, 0.f, 0.f, 0.f}};
  unsigned am = 0xFFu;

  // gi/token prefetch registers (step s+1 loaded during step s)
  u16x8 pg0, pg1, pg2;
  int ptoks[8];
  {
    int tok = utt[r0 + grow];
    const unsigned short* tb = tab + (size_t)tok * GD + c0 + gq * 8;
    pg0 = *(const u16x8*)(tb);
    pg1 = *(const u16x8*)(tb + ED);
    pg2 = *(const u16x8*)(tb + 2 * ED);
    #pragma unroll
    for (int a = 0; a < 2; a++)
      #pragma unroll
      for (int j = 0; j < 4; j++)
        ptoks[a * 4 + j] = utt[r0 + a * 16 + l4 * 4 + j];
  }

  for (int s = 0; s < MSTEPS; s++) {
    const unsigned short* rdb = (s & 1) ? st1 : st0;
    unsigned short* wrb = (s & 1) ? st0 : st1;

    // 1) coalesced agent-scope state load (32KB/WG) -- skipped at s=0 (h=0)
    unsigned long long sld[16];
    if (s > 0) {
      const unsigned long long* sb = (const unsigned long long*)(rdb + (size_t)r0 * ED);
      #pragma unroll
      for (int i = 0; i < 16; i++)
        sld[i] = __hip_atomic_load(sb + i * 256 + tid, __ATOMIC_RELAXED, __HIP_MEMORY_SCOPE_AGENT);
    }

    // 2) park prefetched gi into LDS; snapshot tokens
    {
      char* gb = (char*)gil + grow * (GIST * 2) + gq * 16;
      *(u16x8*)(gb + 0 * 128) = pg0;
      *(u16x8*)(gb + 1 * 128) = pg1;
      *(u16x8*)(gb + 2 * 128) = pg2;
    }
    int tk[8];
    #pragma unroll
    for (int i = 0; i < 8; i++) tk[i] = ptoks[i];

    // 3) state regs -> LDS, XOR-swizzled rows (skipped at s=0)
    if (s > 0) {
      #pragma unroll
      for (int i = 0; i < 16; i++) {
        int o = i * 2048 + tid * 8;
        int row = o >> 10;
        *(unsigned long long*)(sls + (o ^ ((row & 7) << 4))) = sld[i];
      }
    }
    __syncthreads();

    // 4) prefetch next step's gather (hidden under MFMA)
    if (s + 1 < MSTEPS) {
      int tok = utt[(s + 1) * NB + r0 + grow];
      const unsigned short* tb = tab + (size_t)tok * GD + c0 + gq * 8;
      pg0 = *(const u16x8*)(tb);
      pg1 = *(const u16x8*)(tb + ED);
      pg2 = *(const u16x8*)(tb + 2 * ED);
      #pragma unroll
      for (int a = 0; a < 2; a++)
        #pragma unroll
        for (int j = 0; j < 4; j++)
          ptoks[a * 4 + j] = utt[(s + 1) * NB + r0 + a * 16 + l4 * 4 + j];
    }

    // 5) gh = state @ Whh^T  (A from LDS, B from regs); s=0: gh=0 exactly
    f32x4 acc[2][3];
    #pragma unroll
    for (int a = 0; a < 2; a++)
      #pragma unroll
      for (int g = 0; g < 3; g++) acc[a][g] = (f32x4){0.f, 0.f, 0.f, 0.f};
    if (s > 0) {
      #pragma unroll
      for (int kk = 0; kk < 16; kk++) {
        s16x8 av[2];
        #pragma unroll
        for (int a = 0; a < 2; a++) {
          int row = a * 16 + l15;
          int ad = (row * 1024 + kk * 64 + l4 * 16) ^ ((row & 7) << 4);
          av[a] = *(const s16x8*)(sls + ad);
        }
        #pragma unroll
        for (int a = 0; a < 2; a++)
          #pragma unroll
          for (int g = 0; g < 3; g++)
            acc[a][g] = __builtin_amdgcn_mfma_f32_16x16x32_bf16(av[a], bfr[g][kk], acc[a][g], 0, 0, 0);
      }
    }

    // 6) epilogue: gates + blend (f32 master state in regs)
    #pragma unroll
    for (int a = 0; a < 2; a++) {
      #pragma unroll
      for (int j = 0; j < 4; j++) {
        int row = a * 16 + l4 * 4 + j;
        float hr = acc[a][0][j] + bh[0];
        float hz = acc[a][1][j] + bh[1];
        float hn = acc[a][2][j] + bh[2];
        float ir = bf2f(gil[row * GIST + 0 * 64 + wc]);
        float iz = bf2f(gil[row * GIST + 1 * 64 + wc]);
        float in_ = bf2f(gil[row * GIST + 2 * 64 + wc]);
        float r = sigm(ir + hr);
        float z = sigm(iz + hz);
        float nn = tanh_(in_ + r * hn);
        float old = ms[a][j];
        float nu = (1.0f - z) * nn + z * old;
        float res = ((am >> (a * 4 + j)) & 1u) ? nu : old;
        ms[a][j] = res;
        stl[row * STST + wc] = f2bf(res);
        if (tk[a * 4 + j] == termid) am &= ~(1u << (a * 4 + j));
      }
    }
    __syncthreads();

    // 7) cooperative agent-scope store of new state tile (4KB/WG)
    {
      union { u16x8 v; unsigned long long u[2]; } cv;
      cv.v = *(const u16x8*)(stl + grow * STST + gq * 8);
      unsigned long long* dst =
          (unsigned long long*)(wrb + (size_t)(r0 + grow) * ED + c0 + gq * 8);
      __hip_atomic_store(dst, cv.u[0], __ATOMIC_RELAXED, __HIP_MEMORY_SCOPE_AGENT);
      __hip_atomic_store(dst + 1, cv.u[1], __ATOMIC_RELAXED, __HIP_MEMORY_SCOPE_AGENT);
    }

    // 8) per-row-block barrier: 8 per-producer flags in one 64B line.
    //    arrive = 1 release store (parallel across producers);
    //    poll = 4 independent 8B loads covering all 8 flags.
    asm volatile("s_waitcnt vmcnt(0)" ::: "memory");
    __syncthreads();
    if (tid == 0) {
      __hip_atomic_store(fl + cblk, (unsigned)(s + 1), __ATOMIC_RELEASE, __HIP_MEMORY_SCOPE_AGENT);
      const unsigned tgt = (unsigned)(s + 1);
      unsigned long long t0 = __builtin_amdgcn_s_memrealtime();
      int ab = 0, pc = 0;
      for (;;) {
        unsigned long long f01 = __hip_atomic_load((const unsigned long long*)(fl + 0), __ATOMIC_ACQUIRE, __HIP_MEMORY_SCOPE_AGENT);
        unsigned long long f23 = __hip_atomic_load((const unsigned long long*)(fl + 2), __ATOMIC_ACQUIRE, __HIP_MEMORY_SCOPE_AGENT);
        unsigned long long f45 = __hip_atomic_load((const unsigned long long*)(fl + 4), __ATOMIC_ACQUIRE, __HIP_MEMORY_SCOPE_AGENT);
        unsigned long long f67 = __hip_atomic_load((const unsigned long long*)(fl + 6), __ATOMIC_ACQUIRE, __HIP_MEMORY_SCOPE_AGENT);
        unsigned mn = (unsigned)f01;
        mn = mn < (unsigned)(f01 >> 32) ? mn : (unsigned)(f01 >> 32);
        mn = mn < (unsigned)f23 ? mn : (unsigned)f23;
        mn = mn < (unsigned)(f23 >> 32) ? mn : (unsigned)(f23 >> 32);
        mn = mn < (unsigned)f45 ? mn : (unsigned)f45;
        mn = mn < (unsigned)(f45 >> 32) ? mn : (unsigned)(f45 >> 32);
        mn = mn < (unsigned)f67 ? mn : (unsigned)f67;
        mn = mn < (unsigned)(f67 >> 32) ? mn : (unsigned)(f67 >> 32);
        if (mn >= tgt) break;
        if (((++pc) & 15) == 0) {
          if (__hip_atomic_load(abort_g, __ATOMIC_RELAXED, __HIP_MEMORY_SCOPE_AGENT)) { ab = 1; break; }
          if (__builtin_amdgcn_s_memrealtime() - t0 > 20000000ULL) {
            __hip_atomic_store(abort_g, 1, __ATOMIC_RELAXED, __HIP_MEMORY_SCOPE_AGENT);
            ab = 1; break;
          }
        }
      }
      abl = ab;
    }
    __syncthreads();
    if (abl) break;
  }

  // final f32 state -> d_out
  #pragma unroll
  for (int a = 0; a < 2; a++)
    #pragma unroll
    for (int j = 0; j < 4; j++) {
      int n = r0 + a * 16 + l4 * 4 + j;
      out[(size_t)n * ED + c0 + wc] = ms[a][j];
    }
}

__global__ void fail_kernel(float* out) {
  if (threadIdx.x == 0 && blockIdx.x == 0) out[0] = -54321.0f;
}

extern "C" void kernel_launch(void* const* d_in, const int* in_sizes, int n_in,
                              void* d_out, int out_size, void* d_ws, size_t ws_size,
                              hipStream_t stream) {
  const int* utt = (const int*)d_in[0];
  const float* emb = (const float*)d_in[1];
  const float* Wih = (const float*)d_in[2];
  const float* Whh = (const float*)d_in[3];
  const float* bih = (const float*)d_in[4];
  const float* bhh = (const float*)d_in[5];
  const int* term = (const int*)d_in[6];
  float* out = (float*)d_out;
  char* ws = (char*)d_ws;

  const size_t tab_b = (size_t)VS * GD * 2;                 // 98,304,000
  const size_t st_b = (size_t)NB * ED * 2;                  // 1,048,576
  const size_t off_st0 = tab_b;
  const size_t off_st1 = off_st0 + st_b;
  const size_t off_cnt = off_st1 + st_b;
  const size_t need = off_cnt + 8192;

  if (ws_size < need) {  // sentinel: visible failure instead of OOB
    fail_kernel<<<1, 64, 0, stream>>>(out);
    return;
  }

  unsigned short* tab = (unsigned short*)(ws);
  unsigned short* st0 = (unsigned short*)(ws + off_st0);
  unsigned short* st1 = (unsigned short*)(ws + off_st1);
  unsigned* cnt = (unsigned*)(ws + off_cnt);

  // flags + abort zeroed every launch (L3 domain, deterministic).
  // state buffers are strictly written-before-read within each call
  // (s=0 skips the load), so no state memset is needed.
  (void)hipMemsetAsync(cnt, 0, 8192, stream);

  table_kernel<<<dim3(250, 12), 256, 0, stream>>>(emb, Wih, bih, tab);
  gru_kernel<<<256, 256, 0, stream>>>(utt, Whh, bhh, tab, st0, st1,
                                      cnt, term, out);
}

// Round 8
// 1921.310 us; speedup vs baseline: 1.1271x; 1.1271x over previous
//
#include <hip/hip_runtime.h>
#include <stdint.h>
#include <stddef.h>

#define MSTEPS 128
#define NB 1024
#define ED 512
#define GD 1536
#define VS 32000

// GRU decomposition: 64 row-blocks x 16 rows, 4 col-WGs x 128 cols.
// 256 WGs x 512 threads (8 waves), 1 WG/CU. W_hh in VGPRs (192/lane,
// launch_bounds(512,1) so no spill). 2-buffer ping-pong state in L3.
// Exchange protocol = r3-proven: relaxed agent atomics + release fetch_add
// barrier with RELAXED spin (never acquire in a spin: L2-invalidate storm).
#define RB 16
#define CB 128
#define NGR 64   // row-block groups
#define NSH 4    // sharers (col-WGs) per group
#define GIST 392 // gi LDS row stride (elems): 3*128 data + 8 pad
#define STST 136 // stl LDS row stride (elems): 128 data + 8 pad

typedef __attribute__((ext_vector_type(4))) float f32x4;
typedef __attribute__((ext_vector_type(8))) short s16x8;
typedef __attribute__((ext_vector_type(4))) short s16x4;
typedef __attribute__((ext_vector_type(8))) unsigned short u16x8;

__device__ __forceinline__ unsigned short f2bf(float f) {
  unsigned x = __builtin_bit_cast(unsigned, f);
  x = x + 0x7fffu + ((x >> 16) & 1u);
  return (unsigned short)(x >> 16);
}
__device__ __forceinline__ float bf2f(unsigned short u) {
  return __builtin_bit_cast(float, ((unsigned)u) << 16);
}
__device__ __forceinline__ float sigm(float x) { return 1.0f / (1.0f + __expf(-x)); }
__device__ __forceinline__ float tanh_(float x) {
  x = fminf(15.0f, fmaxf(-15.0f, x));
  float e = __expf(-2.0f * x);
  return (1.0f - e) / (1.0f + e);
}

// ---------------- Kernel 1: projected vocab table (r2-proven) ----------------
__global__ __launch_bounds__(256) void table_kernel(
    const float* __restrict__ emb, const float* __restrict__ Wih,
    const float* __restrict__ bih, unsigned short* __restrict__ tab)
{
  __shared__ short Al[128 * 64];
  __shared__ short Bl[128 * 64];
  const int tid = threadIdx.x;
  const int lane = tid & 63;
  const int l15 = lane & 15, l4 = lane >> 4;
  const int wv = tid >> 6;
  const int rh = wv & 1, ch = wv >> 1;
  const int row0 = blockIdx.x * 128;
  const int col0 = blockIdx.y * 128;

  f32x4 acc[4][4];
  #pragma unroll
  for (int m = 0; m < 4; m++)
    #pragma unroll
    for (int n = 0; n < 4; n++) acc[m][n] = (f32x4){0.f, 0.f, 0.f, 0.f};

  for (int ko = 0; ko < ED; ko += 64) {
    #pragma unroll
    for (int i = 0; i < 8; i++) {
      int idx = tid + i * 256;
      int r = idx >> 4, c4 = idx & 15;
      int ba = (r * 128 + c4 * 8) ^ ((r & 7) << 4);
      f32x4 va = *(const f32x4*)(emb + (size_t)(row0 + r) * ED + ko + c4 * 4);
      s16x4 pa;
      pa[0] = (short)f2bf(va[0]); pa[1] = (short)f2bf(va[1]);
      pa[2] = (short)f2bf(va[2]); pa[3] = (short)f2bf(va[3]);
      *(s16x4*)((char*)Al + ba) = pa;
      f32x4 vb = *(const f32x4*)(Wih + (size_t)(col0 + r) * ED + ko + c4 * 4);
      s16x4 pb;
      pb[0] = (short)f2bf(vb[0]); pb[1] = (short)f2bf(vb[1]);
      pb[2] = (short)f2bf(vb[2]); pb[3] = (short)f2bf(vb[3]);
      *(s16x4*)((char*)Bl + ba) = pb;
    }
    __syncthreads();
    #pragma unroll
    for (int kk = 0; kk < 2; kk++) {
      s16x8 af[4], bfv[4];
      #pragma unroll
      for (int m = 0; m < 4; m++) {
        int row = rh * 64 + m * 16 + l15;
        int ad = (row * 128 + kk * 64 + l4 * 16) ^ ((row & 7) << 4);
        af[m] = *(const s16x8*)((char*)Al + ad);
      }
      #pragma unroll
      for (int n = 0; n < 4; n++) {
        int col = ch * 64 + n * 16 + l15;
        int ad = (col * 128 + kk * 64 + l4 * 16) ^ ((col & 7) << 4);
        bfv[n] = *(const s16x8*)((char*)Bl + ad);
      }
      #pragma unroll
      for (int m = 0; m < 4; m++)
        #pragma unroll
        for (int n = 0; n < 4; n++)
          acc[m][n] = __builtin_amdgcn_mfma_f32_16x16x32_bf16(af[m], bfv[n], acc[m][n], 0, 0, 0);
    }
    __syncthreads();
  }

  float bias_n[4];
  #pragma unroll
  for (int n = 0; n < 4; n++) bias_n[n] = bih[col0 + ch * 64 + n * 16 + l15];
  #pragma unroll
  for (int m = 0; m < 4; m++)
    #pragma unroll
    for (int n = 0; n < 4; n++) {
      int colg = col0 + ch * 64 + n * 16 + l15;
      #pragma unroll
      for (int j = 0; j < 4; j++) {
        int rowg = row0 + rh * 64 + m * 16 + l4 * 4 + j;
        tab[(size_t)rowg * GD + colg] = f2bf(acc[m][n][j] + bias_n[n]);
      }
    }
}

// ---------------- Kernel 2: persistent GRU scan ----------------
__global__ __launch_bounds__(512, 1) void gru_kernel(
    const int* __restrict__ utt, const float* __restrict__ Whh,
    const float* __restrict__ bhh, const unsigned short* __restrict__ tab,
    unsigned short* st0, unsigned short* st1,
    unsigned* cnt, const int* __restrict__ termp,
    float* __restrict__ out)
{
  __shared__ __align__(16) char sls[RB * 1024];            // state tile 16KB
  __shared__ __align__(16) unsigned short gil[RB * GIST];  // ~12.3KB
  __shared__ __align__(16) unsigned short stl[RB * STST];  // ~4.3KB
  __shared__ int abl;

  const int tid = threadIdx.x;
  const int lane = tid & 63;
  const int l15 = lane & 15, l4 = lane >> 4;
  const int wv = tid >> 6;                 // wave 0..7
  const int bid = blockIdx.x;
  const int rblk = bid & (NGR - 1);        // 0..63
  const int cblk = bid >> 6;               // 0..3
  const int r0 = rblk * RB, c0 = cblk * CB;
  const int wc = wv * 16 + l15;            // col within WG tile, 0..127
  const int termid = termp[0];

  unsigned* cnt_r = cnt + rblk * 32;       // one 128B line per group
  int* abort_g = (int*)(cnt + 2048);

  // ---- W_hh fragments -> VGPRs (held for all 128 steps; 192 VGPR) ----
  s16x8 bfr[3][16];
  #pragma unroll
  for (int g = 0; g < 3; g++)
    #pragma unroll
    for (int kk = 0; kk < 16; kk++) {
      const float* src = Whh + (size_t)(g * ED + c0 + wc) * ED + kk * 32 + l4 * 8;
      f32x4 v0 = *(const f32x4*)(src);
      f32x4 v1 = *(const f32x4*)(src + 4);
      s16x8 p;
      p[0] = (short)f2bf(v0[0]); p[1] = (short)f2bf(v0[1]);
      p[2] = (short)f2bf(v0[2]); p[3] = (short)f2bf(v0[3]);
      p[4] = (short)f2bf(v1[0]); p[5] = (short)f2bf(v1[1]);
      p[6] = (short)f2bf(v1[2]); p[7] = (short)f2bf(v1[3]);
      bfr[g][kk] = p;
    }

  float bh[3];
  #pragma unroll
  for (int g = 0; g < 3; g++) bh[g] = bhh[g * ED + c0 + wc];

  float ms[4] = {0.f, 0.f, 0.f, 0.f};     // master state rows l4*4+j, col wc
  unsigned am = 0xFu;                      // alive bits, 4 owned rows

  // gather units: 768 x 16B per step; thread handles u0 (+u1 if tid<256)
  const int u0 = tid, u1 = 512 + tid;
  const int r0u0 = u0 / 48, sg0 = u0 % 48;
  const int r0u1 = u1 / 48, sg1 = u1 % 48;

  // prefetch step-0 gather + tokens
  u16x8 pgA, pgB;
  int ptoks[4];
  {
    int tokA = utt[r0 + r0u0];
    pgA = *(const u16x8*)(tab + (size_t)tokA * GD + (sg0 >> 4) * ED + c0 + (sg0 & 15) * 8);
    if (tid < 256) {
      int tokB = utt[r0 + r0u1];
      pgB = *(const u16x8*)(tab + (size_t)tokB * GD + (sg1 >> 4) * ED + c0 + (sg1 & 15) * 8);
    }
    #pragma unroll
    for (int j = 0; j < 4; j++) ptoks[j] = utt[r0 + l4 * 4 + j];
  }

  for (int s = 0; s < MSTEPS; s++) {
    const unsigned short* rdb = (s & 1) ? st1 : st0;
    unsigned short* wrb = (s & 1) ? st0 : st1;

    // 1) coalesced agent-scope state load (16KB/WG) -- skipped at s=0 (h=0)
    unsigned long long sld[4];
    if (s > 0) {
      const unsigned long long* sb = (const unsigned long long*)(rdb + (size_t)r0 * ED);
      #pragma unroll
      for (int k = 0; k < 4; k++)
        sld[k] = __hip_atomic_load(sb + k * 512 + tid, __ATOMIC_RELAXED, __HIP_MEMORY_SCOPE_AGENT);
    }

    // 2) park prefetched gi into LDS; snapshot tokens
    *(u16x8*)(gil + r0u0 * GIST + (sg0 >> 4) * 128 + (sg0 & 15) * 8) = pgA;
    if (tid < 256)
      *(u16x8*)(gil + r0u1 * GIST + (sg1 >> 4) * 128 + (sg1 & 15) * 8) = pgB;
    int tk[4];
    #pragma unroll
    for (int j = 0; j < 4; j++) tk[j] = ptoks[j];

    // 3) state regs -> LDS, XOR-swizzled rows (skipped at s=0)
    if (s > 0) {
      #pragma unroll
      for (int k = 0; k < 4; k++) {
        int i = k * 512 + tid;          // 0..2047 u64 units
        int row = i >> 7;
        int o = row * 1024 + (i & 127) * 8;
        *(unsigned long long*)(sls + (o ^ ((row & 7) << 4))) = sld[k];
      }
    }
    __syncthreads();

    // 4) prefetch next step's gather + tokens (hidden under MFMA)
    if (s + 1 < MSTEPS) {
      int tokA = utt[(s + 1) * NB + r0 + r0u0];
      pgA = *(const u16x8*)(tab + (size_t)tokA * GD + (sg0 >> 4) * ED + c0 + (sg0 & 15) * 8);
      if (tid < 256) {
        int tokB = utt[(s + 1) * NB + r0 + r0u1];
        pgB = *(const u16x8*)(tab + (size_t)tokB * GD + (sg1 >> 4) * ED + c0 + (sg1 & 15) * 8);
      }
      #pragma unroll
      for (int j = 0; j < 4; j++) ptoks[j] = utt[(s + 1) * NB + r0 + l4 * 4 + j];
    }

    // 5) gh = state @ Whh^T  (A from LDS, B from regs); s=0: gh=0 exactly
    f32x4 acc[3];
    #pragma unroll
    for (int g = 0; g < 3; g++) acc[g] = (f32x4){0.f, 0.f, 0.f, 0.f};
    if (s > 0) {
      #pragma unroll
      for (int kk = 0; kk < 16; kk++) {
        int ad = (l15 * 1024 + kk * 64 + l4 * 16) ^ ((l15 & 7) << 4);
        s16x8 av = *(const s16x8*)(sls + ad);
        #pragma unroll
        for (int g = 0; g < 3; g++)
          acc[g] = __builtin_amdgcn_mfma_f32_16x16x32_bf16(av, bfr[g][kk], acc[g], 0, 0, 0);
      }
    }

    // 6) epilogue: gates + blend (f32 master state in regs)
    #pragma unroll
    for (int j = 0; j < 4; j++) {
      int row = l4 * 4 + j;
      float hr = acc[0][j] + bh[0];
      float hz = acc[1][j] + bh[1];
      float hn = acc[2][j] + bh[2];
      float ir = bf2f(gil[row * GIST + 0 * 128 + wc]);
      float iz = bf2f(gil[row * GIST + 1 * 128 + wc]);
      float in_ = bf2f(gil[row * GIST + 2 * 128 + wc]);
      float r = sigm(ir + hr);
      float z = sigm(iz + hz);
      float nn = tanh_(in_ + r * hn);
      float old = ms[j];
      float nu = (1.0f - z) * nn + z * old;
      float res = ((am >> j) & 1u) ? nu : old;
      ms[j] = res;
      stl[row * STST + wc] = f2bf(res);
      if (tk[j] == termid) am &= ~(1u << j);
    }
    __syncthreads();

    // 7) cooperative agent-scope store of new state slice (4KB/WG)
    {
      int srow = tid >> 5, sseg = tid & 31;
      unsigned long long v = *(const unsigned long long*)(stl + srow * STST + sseg * 4);
      unsigned long long* dst =
          (unsigned long long*)(wrb + (size_t)(r0 + srow) * ED + c0 + sseg * 4);
      __hip_atomic_store(dst, v, __ATOMIC_RELAXED, __HIP_MEMORY_SCOPE_AGENT);
    }

    // 8) per-row-block barrier (4 WGs): release fetch_add + RELAXED spin
    //    (r3-proven; acquire-in-spin causes device-wide L2-inv storms)
    asm volatile("s_waitcnt vmcnt(0)" ::: "memory");
    __syncthreads();
    if (tid == 0) {
      __hip_atomic_fetch_add(cnt_r, 1u, __ATOMIC_RELEASE, __HIP_MEMORY_SCOPE_AGENT);
      unsigned target = (unsigned)NSH * (unsigned)(s + 1);
      unsigned long long t0 = __builtin_amdgcn_s_memrealtime();
      int ab = 0, pc = 0;
      while (__hip_atomic_load(cnt_r, __ATOMIC_RELAXED, __HIP_MEMORY_SCOPE_AGENT) < target) {
        if (((++pc) & 63) == 0) {
          if (__hip_atomic_load(abort_g, __ATOMIC_RELAXED, __HIP_MEMORY_SCOPE_AGENT)) { ab = 1; break; }
          if (__builtin_amdgcn_s_memrealtime() - t0 > 20000000ULL) {
            __hip_atomic_store(abort_g, 1, __ATOMIC_RELAXED, __HIP_MEMORY_SCOPE_AGENT);
            ab = 1; break;
          }
        }
      }
      abl = ab;
    }
    __syncthreads();
    if (abl) break;
  }

  // final f32 state -> d_out
  #pragma unroll
  for (int j = 0; j < 4; j++) {
    int n = r0 + l4 * 4 + j;
    out[(size_t)n * ED + c0 + wc] = ms[j];
  }
}

__global__ void fail_kernel(float* out) {
  if (threadIdx.x == 0 && blockIdx.x == 0) out[0] = -54321.0f;
}

extern "C" void kernel_launch(void* const* d_in, const int* in_sizes, int n_in,
                              void* d_out, int out_size, void* d_ws, size_t ws_size,
                              hipStream_t stream) {
  const int* utt = (const int*)d_in[0];
  const float* emb = (const float*)d_in[1];
  const float* Wih = (const float*)d_in[2];
  const float* Whh = (const float*)d_in[3];
  const float* bih = (const float*)d_in[4];
  const float* bhh = (const float*)d_in[5];
  const int* term = (const int*)d_in[6];
  float* out = (float*)d_out;
  char* ws = (char*)d_ws;

  const size_t tab_b = (size_t)VS * GD * 2;                 // 98,304,000
  const size_t st_b = (size_t)NB * ED * 2;                  // 1,048,576
  const size_t off_st0 = tab_b;
  const size_t off_st1 = off_st0 + st_b;
  const size_t off_cnt = off_st1 + st_b;
  const size_t need = off_cnt + 12288;

  if (ws_size < need) {  // sentinel: visible failure instead of OOB
    fail_kernel<<<1, 64, 0, stream>>>(out);
    return;
  }

  unsigned short* tab = (unsigned short*)(ws);
  unsigned short* st0 = (unsigned short*)(ws + off_st0);
  unsigned short* st1 = (unsigned short*)(ws + off_st1);
  unsigned* cnt = (unsigned*)(ws + off_cnt);

  // barrier counters + abort flag zeroed every launch (L3 domain).
  // state buffers are strictly written-before-read within each call
  // (s=0 skips the load), so no state memset is needed.
  (void)hipMemsetAsync(cnt, 0, 12288, stream);

  table_kernel<<<dim3(250, 12), 256, 0, stream>>>(emb, Wih, bih, tab);
  gru_kernel<<<256, 512, 0, stream>>>(utt, Whh, bhh, tab, st0, st1,
                                      cnt, term, out);
}

// Round 10
// 1588.181 us; speedup vs baseline: 1.3636x; 1.2098x over previous
//
#include <hip/hip_runtime.h>
#include <stdint.h>
#include <stddef.h>

#define MSTEPS 128
#define NB 1024
#define ED 512
#define GD 1536
#define VS 32000

// GRU decomposition: 64 row-blocks x 16 rows, 4 col-WGs x 128 cols.
// 256 WGs x 256 threads (4 waves, 1/SIMD, launch_bounds(256,1) -> big VGPR
// budget). W_hh in VGPRs (384/lane, static-indexed). 2-buffer ping-pong in
// L3. Exchange: relaxed agent (sc1) loads/stores; per-producer flags with
// release-arrive + RELAXED spin (acquire-in-spin = L2-inv storm, r7).
// Each WG skips re-loading its own 4KB state slice (LDS->LDS copy).
#define RB 16
#define CB 128
#define NGR 64   // row-block groups
#define NSH 4    // sharers (col-WGs) per group = waves per WG
#define GIST 392 // gi LDS row stride (elems): 3*128 data + 8 pad
#define STST 136 // stl LDS row stride (elems): 128 data + 8 pad

typedef __attribute__((ext_vector_type(4))) float f32x4;
typedef __attribute__((ext_vector_type(8))) short s16x8;
typedef __attribute__((ext_vector_type(4))) short s16x4;
typedef __attribute__((ext_vector_type(8))) unsigned short u16x8;

__device__ __forceinline__ unsigned short f2bf(float f) {
  unsigned x = __builtin_bit_cast(unsigned, f);
  x = x + 0x7fffu + ((x >> 16) & 1u);
  return (unsigned short)(x >> 16);
}
__device__ __forceinline__ float bf2f(unsigned short u) {
  return __builtin_bit_cast(float, ((unsigned)u) << 16);
}
__device__ __forceinline__ float sigm(float x) { return 1.0f / (1.0f + __expf(-x)); }
__device__ __forceinline__ float tanh_(float x) {
  x = fminf(15.0f, fmaxf(-15.0f, x));
  float e = __expf(-2.0f * x);
  return (1.0f - e) / (1.0f + e);
}

// ---------------- Kernel 1: projected vocab table (r2-proven) ----------------
__global__ __launch_bounds__(256) void table_kernel(
    const float* __restrict__ emb, const float* __restrict__ Wih,
    const float* __restrict__ bih, unsigned short* __restrict__ tab)
{
  __shared__ short Al[128 * 64];
  __shared__ short Bl[128 * 64];
  const int tid = threadIdx.x;
  const int lane = tid & 63;
  const int l15 = lane & 15, l4 = lane >> 4;
  const int wv = tid >> 6;
  const int rh = wv & 1, ch = wv >> 1;
  const int row0 = blockIdx.x * 128;
  const int col0 = blockIdx.y * 128;

  f32x4 acc[4][4];
  #pragma unroll
  for (int m = 0; m < 4; m++)
    #pragma unroll
    for (int n = 0; n < 4; n++) acc[m][n] = (f32x4){0.f, 0.f, 0.f, 0.f};

  for (int ko = 0; ko < ED; ko += 64) {
    #pragma unroll
    for (int i = 0; i < 8; i++) {
      int idx = tid + i * 256;
      int r = idx >> 4, c4 = idx & 15;
      int ba = (r * 128 + c4 * 8) ^ ((r & 7) << 4);
      f32x4 va = *(const f32x4*)(emb + (size_t)(row0 + r) * ED + ko + c4 * 4);
      s16x4 pa;
      pa[0] = (short)f2bf(va[0]); pa[1] = (short)f2bf(va[1]);
      pa[2] = (short)f2bf(va[2]); pa[3] = (short)f2bf(va[3]);
      *(s16x4*)((char*)Al + ba) = pa;
      f32x4 vb = *(const f32x4*)(Wih + (size_t)(col0 + r) * ED + ko + c4 * 4);
      s16x4 pb;
      pb[0] = (short)f2bf(vb[0]); pb[1] = (short)f2bf(vb[1]);
      pb[2] = (short)f2bf(vb[2]); pb[3] = (short)f2bf(vb[3]);
      *(s16x4*)((char*)Bl + ba) = pb;
    }
    __syncthreads();
    #pragma unroll
    for (int kk = 0; kk < 2; kk++) {
      s16x8 af[4], bfv[4];
      #pragma unroll
      for (int m = 0; m < 4; m++) {
        int row = rh * 64 + m * 16 + l15;
        int ad = (row * 128 + kk * 64 + l4 * 16) ^ ((row & 7) << 4);
        af[m] = *(const s16x8*)((char*)Al + ad);
      }
      #pragma unroll
      for (int n = 0; n < 4; n++) {
        int col = ch * 64 + n * 16 + l15;
        int ad = (col * 128 + kk * 64 + l4 * 16) ^ ((col & 7) << 4);
        bfv[n] = *(const s16x8*)((char*)Bl + ad);
      }
      #pragma unroll
      for (int m = 0; m < 4; m++)
        #pragma unroll
        for (int n = 0; n < 4; n++)
          acc[m][n] = __builtin_amdgcn_mfma_f32_16x16x32_bf16(af[m], bfv[n], acc[m][n], 0, 0, 0);
    }
    __syncthreads();
  }

  float bias_n[4];
  #pragma unroll
  for (int n = 0; n < 4; n++) bias_n[n] = bih[col0 + ch * 64 + n * 16 + l15];
  #pragma unroll
  for (int m = 0; m < 4; m++)
    #pragma unroll
    for (int n = 0; n < 4; n++) {
      int colg = col0 + ch * 64 + n * 16 + l15;
      #pragma unroll
      for (int j = 0; j < 4; j++) {
        int rowg = row0 + rh * 64 + m * 16 + l4 * 4 + j;
        tab[(size_t)rowg * GD + colg] = f2bf(acc[m][n][j] + bias_n[n]);
      }
    }
}

// ---------------- Kernel 2: persistent GRU scan ----------------
__global__ __launch_bounds__(256, 1) void gru_kernel(
    const int* __restrict__ utt, const float* __restrict__ Whh,
    const float* __restrict__ bhh, const unsigned short* __restrict__ tab,
    unsigned short* st0, unsigned short* st1,
    unsigned* cnt, const int* __restrict__ termp,
    float* __restrict__ out)
{
  __shared__ __align__(16) char sls[RB * 1024];            // state tile 16KB (512 cols)
  __shared__ __align__(16) unsigned short gil[RB * GIST];  // ~12.3KB
  __shared__ __align__(16) unsigned short stl[RB * STST];  // ~4.3KB
  __shared__ int abl;

  const int tid = threadIdx.x;
  const int lane = tid & 63;
  const int l15 = lane & 15, l4 = lane >> 4;
  const int wv = tid >> 6;                 // wave 0..3 (= producer it tracks)
  const int bid = blockIdx.x;
  const int rblk = bid & (NGR - 1);        // 0..63
  const int cblk = bid >> 6;               // 0..3
  const int r0 = rblk * RB, c0 = cblk * CB;
  const int termid = termp[0];

  unsigned* fg = cnt + rblk * 16;          // 4 flags per group, one 64B line
  int* abort_g = (int*)(cnt + 2048);

  if (tid == 0) abl = 0;

  // ---- W_hh fragments -> VGPRs (held for all 128 steps; 384 VGPR) ----
  // bfr[g*2+t][kk]: B-fragment for gate g, col-tile t (col = wv*32+t*16+l15)
  s16x8 bfr[6][16];
  #pragma unroll
  for (int g = 0; g < 3; g++)
    #pragma unroll
    for (int t = 0; t < 2; t++)
      #pragma unroll
      for (int kk = 0; kk < 16; kk++) {
        const float* src =
            Whh + (size_t)(g * ED + c0 + wv * 32 + t * 16 + l15) * ED + kk * 32 + l4 * 8;
        f32x4 v0 = *(const f32x4*)(src);
        f32x4 v1 = *(const f32x4*)(src + 4);
        s16x8 p;
        p[0] = (short)f2bf(v0[0]); p[1] = (short)f2bf(v0[1]);
        p[2] = (short)f2bf(v0[2]); p[3] = (short)f2bf(v0[3]);
        p[4] = (short)f2bf(v1[0]); p[5] = (short)f2bf(v1[1]);
        p[6] = (short)f2bf(v1[2]); p[7] = (short)f2bf(v1[3]);
        bfr[g * 2 + t][kk] = p;
      }

  float bh[3][2];
  #pragma unroll
  for (int g = 0; g < 3; g++)
    #pragma unroll
    for (int t = 0; t < 2; t++)
      bh[g][t] = bhh[g * ED + c0 + wv * 32 + t * 16 + l15];

  float ms[2][4] = {{0.f, 0.f, 0.f, 0.f}, {0.f, 0.f, 0.f, 0.f}};
  unsigned am = 0xFu;                      // alive bits, 4 owned rows (l4*4+j)

  // gather: 768 x 16B units/step; 3 units/thread, constants precomputed
  int grow_[3], gseg8_[3];                 // row, elem offset within gil row
  const unsigned short* gtb_[3];
  #pragma unroll
  for (int k = 0; k < 3; k++) {
    int u = tid + k * 256;
    grow_[k] = u / 48;
    int seg = u % 48;
    gseg8_[k] = seg * 8;
    gtb_[k] = tab + (size_t)(seg >> 4) * ED + c0 + (seg & 15) * 8; // + tok*GD
  }

  // prefetch step-0 gather + tokens
  u16x8 pg[3];
  int ptoks[4];
  #pragma unroll
  for (int k = 0; k < 3; k++) {
    int tok = utt[r0 + grow_[k]];
    pg[k] = *(const u16x8*)(gtb_[k] + (size_t)tok * GD);
  }
  #pragma unroll
  for (int j = 0; j < 4; j++) ptoks[j] = utt[r0 + l4 * 4 + j];

  __syncthreads();

  for (int s = 0; s < MSTEPS; s++) {
    const unsigned short* rdb = (s & 1) ? st1 : st0;
    unsigned short* wrb = (s & 1) ? st0 : st1;

    // 1) park prefetched gi into LDS; snapshot tokens
    #pragma unroll
    for (int k = 0; k < 3; k++)
      *(u16x8*)(gil + grow_[k] * GIST + gseg8_[k]) = pg[k];
    int tk[4];
    #pragma unroll
    for (int j = 0; j < 4; j++) tk[j] = ptoks[j];

    // 2) acquire state tile: wave wv handles producer wv's 4KB slice.
    //    own slice (wv==cblk): LDS->LDS copy from stl. foreign: wait flag
    //    (RELAXED spin) then 8B agent loads. overlaps barrier skew.
    if (s > 0) {
      if (wv == cblk) {
        #pragma unroll
        for (int i = 0; i < 8; i++) {
          int idx = i * 64 + lane;       // 0..511 u64 units
          int row = idx >> 5, c8 = idx & 31;
          unsigned long long v = *(const unsigned long long*)(stl + row * STST + c8 * 4);
          int o = row * 1024 + cblk * 256 + c8 * 8;
          *(unsigned long long*)(sls + (o ^ ((row & 7) << 4))) = v;
        }
      } else {
        const unsigned tgt = (unsigned)s;
        unsigned long long t0 = __builtin_amdgcn_s_memrealtime();
        int pc = 0;
        while (__hip_atomic_load(fg + wv, __ATOMIC_RELAXED, __HIP_MEMORY_SCOPE_AGENT) < tgt) {
          if (((++pc) & 63) == 0) {
            if (__hip_atomic_load(abort_g, __ATOMIC_RELAXED, __HIP_MEMORY_SCOPE_AGENT)) { abl = 1; break; }
            if (__builtin_amdgcn_s_memrealtime() - t0 > 20000000ULL) {
              __hip_atomic_store(abort_g, 1, __ATOMIC_RELAXED, __HIP_MEMORY_SCOPE_AGENT);
              abl = 1; break;
            }
          }
        }
        asm volatile("" ::: "memory");   // compiler fence: loads below stay below
        const unsigned long long* sb =
            (const unsigned long long*)(rdb + (size_t)r0 * ED + wv * CB);
        #pragma unroll
        for (int i = 0; i < 8; i++) {
          int idx = i * 64 + lane;
          int row = idx >> 5, c8 = idx & 31;
          // row stride = ED shorts = 1024B = 128 u64 (r9 bug: was 64)
          unsigned long long v = __hip_atomic_load(sb + row * 128 + c8,
                                                   __ATOMIC_RELAXED, __HIP_MEMORY_SCOPE_AGENT);
          int o = row * 1024 + wv * 256 + c8 * 8;
          *(unsigned long long*)(sls + (o ^ ((row & 7) << 4))) = v;
        }
      }
    }
    __syncthreads();

    // 3) prefetch next step's gather + tokens (hidden under MFMA)
    if (s + 1 < MSTEPS) {
      #pragma unroll
      for (int k = 0; k < 3; k++) {
        int tok = utt[(s + 1) * NB + r0 + grow_[k]];
        pg[k] = *(const u16x8*)(gtb_[k] + (size_t)tok * GD);
      }
      #pragma unroll
      for (int j = 0; j < 4; j++) ptoks[j] = utt[(s + 1) * NB + r0 + l4 * 4 + j];
    }

    // 4) gh = state @ Whh^T  (A from LDS, B from regs); s=0: gh=0 exactly
    f32x4 acc[6];
    #pragma unroll
    for (int u = 0; u < 6; u++) acc[u] = (f32x4){0.f, 0.f, 0.f, 0.f};
    if (s > 0) {
      #pragma unroll
      for (int kk = 0; kk < 16; kk++) {
        int ad = (l15 * 1024 + kk * 64 + l4 * 16) ^ ((l15 & 7) << 4);
        s16x8 av = *(const s16x8*)(sls + ad);
        #pragma unroll
        for (int u = 0; u < 6; u++)
          acc[u] = __builtin_amdgcn_mfma_f32_16x16x32_bf16(av, bfr[u][kk], acc[u], 0, 0, 0);
      }
    }

    // 5) epilogue: gates + blend (f32 master state in regs)
    #pragma unroll
    for (int t = 0; t < 2; t++) {
      #pragma unroll
      for (int j = 0; j < 4; j++) {
        int row = l4 * 4 + j;
        int col = wv * 32 + t * 16 + l15;
        float hr = acc[0 * 2 + t][j] + bh[0][t];
        float hz = acc[1 * 2 + t][j] + bh[1][t];
        float hn = acc[2 * 2 + t][j] + bh[2][t];
        float ir = bf2f(gil[row * GIST + 0 * 128 + col]);
        float iz = bf2f(gil[row * GIST + 1 * 128 + col]);
        float in_ = bf2f(gil[row * GIST + 2 * 128 + col]);
        float r = sigm(ir + hr);
        float z = sigm(iz + hz);
        float nn = tanh_(in_ + r * hn);
        float old = ms[t][j];
        float nu = (1.0f - z) * nn + z * old;
        float res = ((am >> j) & 1u) ? nu : old;
        ms[t][j] = res;
        stl[row * STST + col] = f2bf(res);
      }
    }
    #pragma unroll
    for (int j = 0; j < 4; j++)
      if (tk[j] == termid) am &= ~(1u << j);
    __syncthreads();

    // 6) cooperative agent-scope store of new state slice (4KB/WG)
    {
      int srow = tid >> 4, seg = tid & 15;
      const unsigned long long* src =
          (const unsigned long long*)(stl + srow * STST + seg * 8);
      unsigned long long* dst =
          (unsigned long long*)(wrb + (size_t)(r0 + srow) * ED + c0 + seg * 8);
      __hip_atomic_store(dst, src[0], __ATOMIC_RELAXED, __HIP_MEMORY_SCOPE_AGENT);
      __hip_atomic_store(dst + 1, src[1], __ATOMIC_RELAXED, __HIP_MEMORY_SCOPE_AGENT);
    }

    // 7) arrive: drain stores, barrier, release flag (no spin here --
    //    consumers of step s+1 spin per-wave in phase 2)
    asm volatile("s_waitcnt vmcnt(0)" ::: "memory");
    __syncthreads();
    if (tid == 0)
      __hip_atomic_store(fg + cblk, (unsigned)(s + 1), __ATOMIC_RELEASE, __HIP_MEMORY_SCOPE_AGENT);
    if (abl) break;
  }

  // final f32 state -> d_out
  #pragma unroll
  for (int t = 0; t < 2; t++)
    #pragma unroll
    for (int j = 0; j < 4; j++) {
      int n = r0 + l4 * 4 + j;
      out[(size_t)n * ED + c0 + wv * 32 + t * 16 + l15] = ms[t][j];
    }
}

__global__ void fail_kernel(float* out) {
  if (threadIdx.x == 0 && blockIdx.x == 0) out[0] = -54321.0f;
}

extern "C" void kernel_launch(void* const* d_in, const int* in_sizes, int n_in,
                              void* d_out, int out_size, void* d_ws, size_t ws_size,
                              hipStream_t stream) {
  const int* utt = (const int*)d_in[0];
  const float* emb = (const float*)d_in[1];
  const float* Wih = (const float*)d_in[2];
  const float* Whh = (const float*)d_in[3];
  const float* bih = (const float*)d_in[4];
  const float* bhh = (const float*)d_in[5];
  const int* term = (const int*)d_in[6];
  float* out = (float*)d_out;
  char* ws = (char*)d_ws;

  const size_t tab_b = (size_t)VS * GD * 2;                 // 98,304,000
  const size_t st_b = (size_t)NB * ED * 2;                  // 1,048,576
  const size_t off_st0 = tab_b;
  const size_t off_st1 = off_st0 + st_b;
  const size_t off_cnt = off_st1 + st_b;
  const size_t need = off_cnt + 12288;

  if (ws_size < need) {  // sentinel: visible failure instead of OOB
    fail_kernel<<<1, 64, 0, stream>>>(out);
    return;
  }

  unsigned short* tab = (unsigned short*)(ws);
  unsigned short* st0 = (unsigned short*)(ws + off_st0);
  unsigned short* st1 = (unsigned short*)(ws + off_st1);
  unsigned* cnt = (unsigned*)(ws + off_cnt);

  // flags + abort zeroed every launch (recorded in the graph, so every
  // replay re-zeroes). state buffers are written-before-read within each
  // call (s=0 skips the load), so no state memset is needed.
  (void)hipMemsetAsync(cnt, 0, 12288, stream);

  table_kernel<<<dim3(250, 12), 256, 0, stream>>>(emb, Wih, bih, tab);
  gru_kernel<<<256, 256, 0, stream>>>(utt, Whh, bhh, tab, st0, st1,
                                      cnt, term, out);
}